// Round 1
// 365.448 us; speedup vs baseline: 1.0314x; 1.0314x over previous
//
#include <hip/hip_runtime.h>
#include <stdint.h>

typedef unsigned short u16;
typedef unsigned int   u32;
typedef short bf16x8 __attribute__((ext_vector_type(8)));
typedef float f32x4  __attribute__((ext_vector_type(4)));

// workspace layout (bytes)
static constexpr size_t OFF_H1  = 0;                        // u16[4096*4096]  32 MB
static constexpr size_t OFF_W1B = 33554432;                 // u16[4096*256]    2 MB
static constexpr size_t OFF_W2P = 35651584;                 // float[65536]   256 KB
static constexpr size_t OFF_W3P = 35913728;                 // float[65536]   256 KB

__device__ __forceinline__ u32 f2b_pair(float lo, float hi) {
  u32 a = __builtin_bit_cast(u32, lo);
  a = (a + 0x7FFFu + ((a >> 16) & 1u)) >> 16;
  u32 b = __builtin_bit_cast(u32, hi);
  b = (b + 0x7FFFu + ((b >> 16) & 1u)) >> 16;
  return a | (b << 16);
}
__device__ __forceinline__ float b2f(u16 u) {
  return __builtin_bit_cast(float, (u32)u << 16);
}
__device__ __forceinline__ uint4 pack8(const float* gp) {
  float4 v0 = *(const float4*)gp;
  float4 v1 = *(const float4*)(gp + 4);
  uint4 w;
  w.x = f2b_pair(v0.x, v0.y); w.y = f2b_pair(v0.z, v0.w);
  w.z = f2b_pair(v1.x, v1.y); w.w = f2b_pair(v1.z, v1.w);
  return w;
}

// ---------------------------------------------------------------------------
// prep: W1 used block-diag -> bf16 w1b [kb*256+n][k].  512 blocks only.
// (The W2/W3 diagonal gathers moved into l1_gemm's grid tail — they are only
// consumed by l23, so they can overlap the GEMM instead of serializing here.)
// ---------------------------------------------------------------------------
__global__ __launch_bounds__(256) void prep(const float* __restrict__ W1,
                                            u16* __restrict__ w1b) {
  const size_t e = ((size_t)blockIdx.x * 256 + threadIdx.x) * 8;  // w1b elem idx
  const int row = (int)(e >> 8);                             // 0..4095 (= kb*256+n)
  const int col = (int)(e & 255);                            // k within block
  const int kb  = row >> 8;
  *(uint4*)(w1b + e) = pack8(W1 + (size_t)row * 4096 + kb * 256 + col);
}

// ---------------------------------------------------------------------------
// Layer 1: 16 block-diagonal GEMMs. A = X fp32, converted to bf16 during
// staging (reg roundtrip); B = pre-packed bf16 w1b via global_load_lds.
// Tile 128x128, BK=64, 4 waves (2x2), acc[4][4]/wave, 16x16x32 MFMA,
// XOR-swizzled LDS.
//
// Grid = 1024 gemm blocks + 512 gather blocks (tail; W2/W3 diag packs).
// Gemm blockIdx swizzle: the two nt halves of a (kb,mt) pair read the SAME
// 128x256 A-tile. Default round-robin puts adjacent blocks on different XCDs
// (private L2s) -> A fetched twice through L3. Remap so the pair lands on the
// same XCD (bx and bx+8), 8 dispatch slots apart -> second read is an L2 hit.
// Side effect: each XCD owns kb in {2*xcd, 2*xcd+1}, so the w1b B-panels are
// also L2-resident per XCD.
// ---------------------------------------------------------------------------
__global__ __launch_bounds__(256) void l1_gemm(const float* __restrict__ X,
                                               const u16* __restrict__ w1b,
                                               const float* __restrict__ b1,
                                               u16* __restrict__ h1,
                                               const float* __restrict__ W2,
                                               const float* __restrict__ W3,
                                               float* __restrict__ w2p,
                                               float* __restrict__ w3p) {
  __shared__ u16 As[128 * 64];
  __shared__ u16 Bs[128 * 64];

  const int bx  = blockIdx.x;
  const int tid = threadIdx.x;

  if (bx >= 1024) {
    // W2/W3 diagonal gathers (consumed only by l23_fused, which launches
    // after this kernel). Latency-bound scatter reads; overlap the GEMM.
    const int t = (bx - 1024) * 256 + tid;                   // 0..131071
    const int r = t & 255, k = (t >> 8) & 15, i = (t >> 12) & 15;
    if (t < 65536) {
      w2p[t] = (k <= i) ? W2[(size_t)(i * 256 + r) * 4096 + k * 256 + r] : 0.0f;
    } else {
      w3p[t - 65536] = W3[(size_t)(i * 256 + r) * 4096 + k * 256 + r];
    }
    return;
  }

  const int lane = tid & 63;
  const int wave = tid >> 6;
  const int wm   = wave & 1;
  const int wn   = wave >> 1;
  const int rl   = lane & 15;
  const int quad = lane >> 4;

  // XCD-pair swizzle: xcd = bx & 7 (HW round-robin heuristic).
  const int xcd  = bx & 7;
  const int g    = bx >> 3;                 // 0..127 sequence slot on this xcd
  const int pair = xcd * 64 + (g >> 1);     // 0..511  (16 kb x 32 mt)
  const int nt   = g & 1;
  const int kb   = pair >> 5;
  const int mt   = pair & 31;
  const int m0   = mt * 128;
  const int n0   = nt * 128;

  // B staging lane roles (global_load_lds): 8 rows x 8 chunks x 16B per inst
  const int sr = lane >> 3;           // row within 8-row group
  const int sc = lane & 7;            // LDS slot this lane fills
  const int cc = sc ^ sr;             // global chunk -> slot XOR swizzle

  const float* Abase = X   + (size_t)m0 * 4096 + kb * 256;    // row stride 4096
  const u16*   Bbase = w1b + (size_t)(kb * 256 + n0) * 256;   // row stride 256

  f32x4 acc[4][4] = {};

  for (int kk0 = 0; kk0 < 256; kk0 += 64) {
    // B first: DMA in flight while we do the A fp32->bf16 pack
    #pragma unroll
    for (int g2 = 0; g2 < 4; ++g2) {
      const int rb = wave * 32 + g2 * 8;           // wave-uniform row base
      const int r  = rb + sr;
      __builtin_amdgcn_global_load_lds(
          (const __attribute__((address_space(1))) void*)(Bbase + (size_t)r * 256 + kk0 + cc * 8),
          (__attribute__((address_space(3))) void*)(Bs + rb * 64),
          16, 0, 0);
    }
    // A: load fp32, round-to-nearest-even pack to bf16, swizzled ds_write
    #pragma unroll
    for (int c = 0; c < 4; ++c) {
      const int f    = c * 256 + tid;
      const int row  = f >> 3;
      const int kd   = f & 7;
      const int slot = kd ^ (row & 7);
      *(uint4*)(As + row * 64 + slot * 8) =
          pack8(Abase + (size_t)row * 4096 + kk0 + kd * 8);
    }
    __syncthreads();

    #pragma unroll
    for (int k32 = 0; k32 < 64; k32 += 32) {
      const int kdq = (k32 >> 3) + quad;           // chunk this quad consumes
      bf16x8 af[4], bfr[4];
      #pragma unroll
      for (int mi = 0; mi < 4; ++mi) {
        const int row = wm * 64 + mi * 16 + rl;
        af[mi] = *(const bf16x8*)(As + row * 64 + (kdq ^ (row & 7)) * 8);
      }
      #pragma unroll
      for (int ni = 0; ni < 4; ++ni) {
        const int row = wn * 64 + ni * 16 + rl;
        bfr[ni] = *(const bf16x8*)(Bs + row * 64 + (kdq ^ (row & 7)) * 8);
      }
      #pragma unroll
      for (int mi = 0; mi < 4; ++mi)
        #pragma unroll
        for (int ni = 0; ni < 4; ++ni)
          acc[mi][ni] = __builtin_amdgcn_mfma_f32_16x16x32_bf16(
              af[mi], bfr[ni], acc[mi][ni], 0, 0, 0);
    }
    __syncthreads();
  }

  // epilogue: bias + relu, store bf16.  C/D: col = lane&15, row = quad*4 + reg.
  #pragma unroll
  for (int ni = 0; ni < 4; ++ni) {
    const int col  = n0 + wn * 64 + ni * 16 + rl;      // 0..255 within block kb
    const float bias = b1[kb * 256 + col];
    #pragma unroll
    for (int mi = 0; mi < 4; ++mi) {
      const int rowb = m0 + wm * 64 + mi * 16 + quad * 4;
      #pragma unroll
      for (int rg = 0; rg < 4; ++rg) {
        float v = acc[mi][ni][rg] + bias;
        v = fmaxf(v, 0.0f);
        u32 u = __builtin_bit_cast(u32, v);
        u = (u + 0x7FFFu + ((u >> 16) & 1u)) >> 16;
        h1[(size_t)(rowb + rg) * 4096 + kb * 256 + col] = (u16)u;
      }
    }
  }
}

// ---------------------------------------------------------------------------
// Layers 2+3 fused, per-(b,r) chains. 256 threads = r lanes, 4 batch rows/thread.
// Layer 2 is triangular in k; update st[] in place with i descending.
// ---------------------------------------------------------------------------
__global__ __launch_bounds__(256) void l23_fused(const u16* __restrict__ h1,
                                                 const float* __restrict__ w2p,
                                                 const float* __restrict__ w3p,
                                                 const float* __restrict__ b2,
                                                 const float* __restrict__ b3,
                                                 float* __restrict__ out) {
  const int r = threadIdx.x;
  const size_t b0 = (size_t)blockIdx.x * 4;

  float st[16][4];
  #pragma unroll
  for (int k = 0; k < 16; ++k)
    #pragma unroll
    for (int b = 0; b < 4; ++b)
      st[k][b] = b2f(h1[(b0 + b) * 4096 + k * 256 + r]);

  #pragma unroll
  for (int i = 15; i >= 0; --i) {
    const float bias = b2[i * 256 + r];
    float acc[4] = {bias, bias, bias, bias};
    #pragma unroll
    for (int k = 0; k <= i; ++k) {
      const float w = w2p[(i * 16 + k) * 256 + r];
      #pragma unroll
      for (int b = 0; b < 4; ++b) acc[b] = fmaf(w, st[k][b], acc[b]);
    }
    #pragma unroll
    for (int b = 0; b < 4; ++b) st[i][b] = fmaxf(acc[b], 0.0f);
  }

  #pragma unroll
  for (int q = 0; q < 16; ++q) {
    const float bias = b3[q * 256 + r];
    float acc[4] = {bias, bias, bias, bias};
    #pragma unroll
    for (int k = 0; k < 16; ++k) {
      const float w = w3p[(q * 16 + k) * 256 + r];
      #pragma unroll
      for (int b = 0; b < 4; ++b) acc[b] = fmaf(w, st[k][b], acc[b]);
    }
    #pragma unroll
    for (int b = 0; b < 4; ++b)
      out[(b0 + b) * 4096 + q * 256 + r] = acc[b];
  }
}

extern "C" void kernel_launch(void* const* d_in, const int* in_sizes, int n_in,
                              void* d_out, int out_size, void* d_ws, size_t ws_size,
                              hipStream_t stream) {
  const float* x  = (const float*)d_in[0];
  const float* W1 = (const float*)d_in[1];
  const float* b1 = (const float*)d_in[2];
  const float* W2 = (const float*)d_in[3];
  const float* b2 = (const float*)d_in[4];
  const float* W3 = (const float*)d_in[5];
  const float* b3 = (const float*)d_in[6];
  float* out = (float*)d_out;

  char* ws  = (char*)d_ws;
  u16*   h1  = (u16*)(ws + OFF_H1);
  u16*   w1b = (u16*)(ws + OFF_W1B);
  float* w2p = (float*)(ws + OFF_W2P);
  float* w3p = (float*)(ws + OFF_W3P);

  prep     <<< 512, 256, 0, stream>>>(W1, w1b);
  l1_gemm  <<<1536, 256, 0, stream>>>(x, w1b, b1, h1, W2, W3, w2p, w3p);
  l23_fused<<<1024, 256, 0, stream>>>(h1, w2p, w3p, b2, b3, out);
}